// Round 3
// baseline (572.431 us; speedup 1.0000x reference)
//
#include <hip/hip_runtime.h>
#include <math.h>

#define HH 56
#define WW 56
#define CC 384
#define NHEADS 12
#define DHEAD 32
#define HID 1536

__device__ __forceinline__ float gelu_exact(float v) {
    return 0.5f * v * (1.0f + erff(v * 0.70710678118654752f));
}

// ---------------- LayerNorm: one wave (64 lanes) per row of 384 ----------------
__global__ __launch_bounds__(256) void ln_kernel(const float* __restrict__ x,
        const float* __restrict__ g, const float* __restrict__ b,
        float* __restrict__ y, int nrows) {
    int wid = (blockIdx.x * 256 + threadIdx.x) >> 6;
    int lane = threadIdx.x & 63;
    if (wid >= nrows) return;
    const float* xr = x + (size_t)wid * CC;
    float v[6];
    float s = 0.f, s2 = 0.f;
    #pragma unroll
    for (int j = 0; j < 6; ++j) {
        v[j] = xr[lane + j * 64];
        s += v[j]; s2 += v[j] * v[j];
    }
    #pragma unroll
    for (int o = 1; o < 64; o <<= 1) {
        s  += __shfl_xor(s, o, 64);
        s2 += __shfl_xor(s2, o, 64);
    }
    float mu  = s * (1.0f / CC);
    float var = s2 * (1.0f / CC) - mu * mu;
    float rs  = rsqrtf(var + 1e-5f);
    float* yr = y + (size_t)wid * CC;
    #pragma unroll
    for (int j = 0; j < 6; ++j) {
        int c = lane + j * 64;
        yr[c] = (v[j] - mu) * rs * g[c] + b[c];
    }
}

// ---------------- Tiled f32 GEMM: C = A[MxK] @ W[KxN] + bias, epilogues ----------------
// EPI: 0 = bias only, 1 = bias + exact gelu, 2 = bias + residual add
template<int EPI>
__global__ __launch_bounds__(256) void gemm_f32(const float* __restrict__ A,
        const float* __restrict__ Wm, const float* __restrict__ bias,
        const float* __restrict__ res, float* __restrict__ out,
        int M, int N, int K) {
    __shared__ float As[16][68];   // [k][m], padded for alignment
    __shared__ float Bs[16][68];   // [k][n]
    int tid = threadIdx.x;
    int m0 = blockIdx.y * 64;
    int n0 = blockIdx.x * 64;
    int ty = tid >> 4, tx = tid & 15;
    float acc[4][4] = {};
    int arow = tid >> 2, akq = (tid & 3) << 2;
    int brow = tid >> 4, bnq = (tid & 15) << 2;
    for (int k0 = 0; k0 < K; k0 += 16) {
        float4 a4 = *reinterpret_cast<const float4*>(&A[(size_t)(m0 + arow) * K + k0 + akq]);
        float4 b4 = *reinterpret_cast<const float4*>(&Wm[(size_t)(k0 + brow) * N + n0 + bnq]);
        As[akq + 0][arow] = a4.x; As[akq + 1][arow] = a4.y;
        As[akq + 2][arow] = a4.z; As[akq + 3][arow] = a4.w;
        *reinterpret_cast<float4*>(&Bs[brow][bnq]) = b4;
        __syncthreads();
        #pragma unroll
        for (int kk = 0; kk < 16; ++kk) {
            float4 av = *reinterpret_cast<const float4*>(&As[kk][ty * 4]);
            float4 bv = *reinterpret_cast<const float4*>(&Bs[kk][tx * 4]);
            float aa[4] = {av.x, av.y, av.z, av.w};
            float bb[4] = {bv.x, bv.y, bv.z, bv.w};
            #pragma unroll
            for (int i = 0; i < 4; ++i)
                #pragma unroll
                for (int j = 0; j < 4; ++j)
                    acc[i][j] = fmaf(aa[i], bb[j], acc[i][j]);
        }
        __syncthreads();
    }
    #pragma unroll
    for (int i = 0; i < 4; ++i) {
        int gm = m0 + ty * 4 + i;
        #pragma unroll
        for (int j = 0; j < 4; ++j) {
            int gn = n0 + tx * 4 + j;
            float v = acc[i][j] + bias[gn];
            if (EPI == 1) v = gelu_exact(v);
            if (EPI == 2) v += res[(size_t)gm * N + gn];
            out[(size_t)gm * N + gn] = v;
        }
    }
}

// ---------------- Neighborhood attention: 1 thread per (query position, head) ----------------
// qkv row layout: row = pos (b*H*W + hy*W + wx), cols [0,384)=q, [384,768)=k, [768,1152)=v
__global__ __launch_bounds__(256) void nattn_kernel(const float* __restrict__ qkv,
        const float* __restrict__ rpb, float* __restrict__ outp) {
    int tid = blockIdx.x * 256 + threadIdx.x;
    int n   = tid % NHEADS;
    int pos = tid / NHEADS;
    int wx = pos % WW;
    int hy = (pos / WW) % HH;
    int sh = hy - 3; sh = sh < 0 ? 0 : (sh > HH - 7 ? HH - 7 : sh);
    int sw = wx - 3; sw = sw < 0 ? 0 : (sw > WW - 7 ? WW - 7 : sw);
    const float scale = 0.17677669529663687f; // 1/sqrt(32)
    const float* qb = qkv + (size_t)pos * 1152 + n * 32;
    float q[32];
    #pragma unroll
    for (int i = 0; i < 8; ++i) {
        float4 t = reinterpret_cast<const float4*>(qb)[i];
        q[4*i] = t.x * scale; q[4*i+1] = t.y * scale;
        q[4*i+2] = t.z * scale; q[4*i+3] = t.w * scale;
    }
    int posbase = pos - hy * WW - wx; // b*H*W
    const float* rp = rpb + n * 169;  // 13*13
    float sc[49];
    float mx = -1e30f;
    for (int jh = 0; jh < 7; ++jh) {
        int iy = sh + jh;
        for (int jw = 0; jw < 7; ++jw) {
            int ix = sw + jw;
            int nrow = posbase + iy * WW + ix;
            const float* kb = qkv + (size_t)nrow * 1152 + 384 + n * 32;
            float d = 0.f;
            #pragma unroll
            for (int i = 0; i < 8; ++i) {
                float4 t = reinterpret_cast<const float4*>(kb)[i];
                d += q[4*i] * t.x + q[4*i+1] * t.y + q[4*i+2] * t.z + q[4*i+3] * t.w;
            }
            d += rp[(iy - hy + 6) * 13 + (ix - wx + 6)];
            sc[jh * 7 + jw] = d;
            mx = fmaxf(mx, d);
        }
    }
    float se = 0.f;
    #pragma unroll
    for (int j = 0; j < 49; ++j) { sc[j] = __expf(sc[j] - mx); se += sc[j]; }
    float inv = 1.0f / se;
    float o[32] = {};
    for (int jh = 0; jh < 7; ++jh) {
        int iy = sh + jh;
        for (int jw = 0; jw < 7; ++jw) {
            int ix = sw + jw;
            int nrow = posbase + iy * WW + ix;
            const float* vb = qkv + (size_t)nrow * 1152 + 768 + n * 32;
            float w = sc[jh * 7 + jw] * inv;
            #pragma unroll
            for (int i = 0; i < 8; ++i) {
                float4 t = reinterpret_cast<const float4*>(vb)[i];
                o[4*i]   = fmaf(w, t.x, o[4*i]);
                o[4*i+1] = fmaf(w, t.y, o[4*i+1]);
                o[4*i+2] = fmaf(w, t.z, o[4*i+2]);
                o[4*i+3] = fmaf(w, t.w, o[4*i+3]);
            }
        }
    }
    float* ob = outp + (size_t)pos * CC + n * 32;
    #pragma unroll
    for (int i = 0; i < 8; ++i) {
        float4 t = {o[4*i], o[4*i+1], o[4*i+2], o[4*i+3]};
        reinterpret_cast<float4*>(ob)[i] = t;
    }
}

extern "C" void kernel_launch(void* const* d_in, const int* in_sizes, int n_in,
                              void* d_out, int out_size, void* d_ws, size_t ws_size,
                              hipStream_t stream) {
    const float* x     = (const float*)d_in[0];
    const float* ln1g  = (const float*)d_in[1];
    const float* ln1b  = (const float*)d_in[2];
    const float* wqkv  = (const float*)d_in[3];
    const float* bqkv  = (const float*)d_in[4];
    const float* rpb   = (const float*)d_in[5];
    const float* wproj = (const float*)d_in[6];
    const float* bproj = (const float*)d_in[7];
    const float* ln2g  = (const float*)d_in[8];
    const float* ln2b  = (const float*)d_in[9];
    const float* w1    = (const float*)d_in[10];
    const float* b1    = (const float*)d_in[11];
    const float* w2    = (const float*)d_in[12];
    const float* b2    = (const float*)d_in[13];
    float* out = (float*)d_out;

    const int Nrows = 2 * HH * WW; // 6272
    char* ws = (char*)d_ws;
    // region 0: qkv (28.9MB) then reused as h1 (38.5MB)
    float* qkv = (float*)(ws);
    float* h1  = qkv;
    // region 1: y1 / attn_out / y2 (9.63MB)
    float* y1  = (float*)(ws + 38535168);
    // region 2: x2 (9.63MB)
    float* x2  = (float*)(ws + 38535168 + 9633792);

    // 1. LN1: y1 = layer_norm(x)
    ln_kernel<<<Nrows / 4, 256, 0, stream>>>(x, ln1g, ln1b, y1, Nrows);
    // 2. qkv = y1 @ w_qkv + b_qkv   (6272 x 384 x 1152)
    gemm_f32<0><<<dim3(1152 / 64, Nrows / 64), 256, 0, stream>>>(y1, wqkv, bqkv, nullptr, qkv, Nrows, 1152, 384);
    // 3. neighborhood attention -> attn_out (reuse y1 region)
    float* attn_out = y1;
    nattn_kernel<<<(Nrows * NHEADS) / 256, 256, 0, stream>>>(qkv, rpb, attn_out);
    // 4. x2 = x + attn_out @ w_proj + b_proj   (6272 x 384 x 384)
    gemm_f32<2><<<dim3(384 / 64, Nrows / 64), 256, 0, stream>>>(attn_out, wproj, bproj, x, x2, Nrows, 384, 384);
    // 5. LN2: y2 = layer_norm(x2) (reuse y1 region)
    float* y2 = y1;
    ln_kernel<<<Nrows / 4, 256, 0, stream>>>(x2, ln2g, ln2b, y2, Nrows);
    // 6. h1 = gelu(y2 @ w1 + b1)   (6272 x 384 x 1536)
    gemm_f32<1><<<dim3(HID / 64, Nrows / 64), 256, 0, stream>>>(y2, w1, b1, nullptr, h1, Nrows, HID, 384);
    // 7. out = x2 + h1 @ w2 + b2   (6272 x 1536 x 384)
    gemm_f32<2><<<dim3(384 / 64, Nrows / 64), 256, 0, stream>>>(h1, w2, b2, x2, out, Nrows, 384, HID);
}

// Round 4
// 397.606 us; speedup vs baseline: 1.4397x; 1.4397x over previous
//
#include <hip/hip_runtime.h>
#include <math.h>

#define HH 56
#define WW 56
#define CC 384
#define NHEADS 12
#define DHEAD 32
#define HID 1536

__device__ __forceinline__ float gelu_exact(float v) {
    return 0.5f * v * (1.0f + erff(v * 0.70710678118654752f));
}

// ---------------- LayerNorm: one wave (64 lanes) per row of 384 ----------------
__global__ __launch_bounds__(256) void ln_kernel(const float* __restrict__ x,
        const float* __restrict__ g, const float* __restrict__ b,
        float* __restrict__ y, int nrows) {
    int wid = (blockIdx.x * 256 + threadIdx.x) >> 6;
    int lane = threadIdx.x & 63;
    if (wid >= nrows) return;
    const float* xr = x + (size_t)wid * CC;
    float v[6];
    float s = 0.f, s2 = 0.f;
    #pragma unroll
    for (int j = 0; j < 6; ++j) {
        v[j] = xr[lane + j * 64];
        s += v[j]; s2 += v[j] * v[j];
    }
    #pragma unroll
    for (int o = 1; o < 64; o <<= 1) {
        s  += __shfl_xor(s, o, 64);
        s2 += __shfl_xor(s2, o, 64);
    }
    float mu  = s * (1.0f / CC);
    float var = s2 * (1.0f / CC) - mu * mu;
    float rs  = rsqrtf(var + 1e-5f);
    float* yr = y + (size_t)wid * CC;
    #pragma unroll
    for (int j = 0; j < 6; ++j) {
        int c = lane + j * 64;
        yr[c] = (v[j] - mu) * rs * g[c] + b[c];
    }
}

// ---------------- Tiled f32 GEMM: C = A[MxK] @ W[KxN] + bias, epilogues ----------------
// EPI: 0 = bias only, 1 = bias + exact gelu, 2 = bias + residual add
template<int EPI>
__global__ __launch_bounds__(256) void gemm_f32(const float* __restrict__ A,
        const float* __restrict__ Wm, const float* __restrict__ bias,
        const float* __restrict__ res, float* __restrict__ out,
        int M, int N, int K) {
    __shared__ float As[16][68];   // [k][m], padded for alignment
    __shared__ float Bs[16][68];   // [k][n]
    int tid = threadIdx.x;
    int m0 = blockIdx.y * 64;
    int n0 = blockIdx.x * 64;
    int ty = tid >> 4, tx = tid & 15;
    float acc[4][4] = {};
    int arow = tid >> 2, akq = (tid & 3) << 2;
    int brow = tid >> 4, bnq = (tid & 15) << 2;
    for (int k0 = 0; k0 < K; k0 += 16) {
        float4 a4 = *reinterpret_cast<const float4*>(&A[(size_t)(m0 + arow) * K + k0 + akq]);
        float4 b4 = *reinterpret_cast<const float4*>(&Wm[(size_t)(k0 + brow) * N + n0 + bnq]);
        As[akq + 0][arow] = a4.x; As[akq + 1][arow] = a4.y;
        As[akq + 2][arow] = a4.z; As[akq + 3][arow] = a4.w;
        *reinterpret_cast<float4*>(&Bs[brow][bnq]) = b4;
        __syncthreads();
        #pragma unroll
        for (int kk = 0; kk < 16; ++kk) {
            float4 av = *reinterpret_cast<const float4*>(&As[kk][ty * 4]);
            float4 bv = *reinterpret_cast<const float4*>(&Bs[kk][tx * 4]);
            float aa[4] = {av.x, av.y, av.z, av.w};
            float bb[4] = {bv.x, bv.y, bv.z, bv.w};
            #pragma unroll
            for (int i = 0; i < 4; ++i)
                #pragma unroll
                for (int j = 0; j < 4; ++j)
                    acc[i][j] = fmaf(aa[i], bb[j], acc[i][j]);
        }
        __syncthreads();
    }
    #pragma unroll
    for (int i = 0; i < 4; ++i) {
        int gm = m0 + ty * 4 + i;
        #pragma unroll
        for (int j = 0; j < 4; ++j) {
            int gn = n0 + tx * 4 + j;
            float v = acc[i][j] + bias[gn];
            if (EPI == 1) v = gelu_exact(v);
            if (EPI == 2) v += res[(size_t)gm * N + gn];
            out[(size_t)gm * N + gn] = v;
        }
    }
}

// ---------------- Tiled neighborhood attention ----------------
// One block per (8x8 query tile, head, batch). 256 threads: 4 lanes per query
// (8 dims each). Stage 14x14 K-halo in LDS, compute scores (shfl-reduce over
// the 4 lanes), softmax in-register, then re-stage V into the SAME LDS buffer
// and accumulate PV. LDS = 196*36*4 + 676 B = 28.9 KB -> ~5 blocks/CU.
__global__ __launch_bounds__(256) void nattn_tile(const float* __restrict__ qkv,
        const float* __restrict__ rpb, float* __restrict__ outp) {
    __shared__ float Ks[196][36];   // K then V (phase-reused), padded stride 36
    __shared__ float bs[169];       // rpb row for this head
    int tile = blockIdx.x;          // 0..48
    int head = blockIdx.y;          // 0..11
    int bat  = blockIdx.z;          // 0..1
    int tly = tile / 7, tlx = tile % 7;
    int h0 = tly * 8 - 3; h0 = h0 < 0 ? 0 : (h0 > 42 ? 42 : h0);
    int w0 = tlx * 8 - 3; w0 = w0 < 0 ? 0 : (w0 > 42 ? 42 : w0);
    int t = threadIdx.x;
    int posbase = bat * (HH * WW);

    for (int i = t; i < 169; i += 256) bs[i] = rpb[head * 169 + i];
    // stage K: 196 rows x 32 floats (8 float4 segs per row)
    for (int idx = t; idx < 196 * 8; idx += 256) {
        int row = idx >> 3, seg = idx & 7;
        int iy = h0 + row / 14, ix = w0 + row % 14;
        int gpos = posbase + iy * WW + ix;
        *reinterpret_cast<float4*>(&Ks[row][seg * 4]) =
            *reinterpret_cast<const float4*>(&qkv[(size_t)gpos * 1152 + 384 + head * 32 + seg * 4]);
    }
    __syncthreads();

    int q = t >> 2, c = t & 3;                 // query 0..63, dim-chunk 0..3
    int qy = tly * 8 + (q >> 3), qx = tlx * 8 + (q & 7);
    int qpos = posbase + qy * WW + qx;
    const float scale = 0.17677669529663687f;  // 1/sqrt(32)
    float qr[8];
    {
        const float* qb = &qkv[(size_t)qpos * 1152 + head * 32 + c * 8];
        float4 a = reinterpret_cast<const float4*>(qb)[0];
        float4 b = reinterpret_cast<const float4*>(qb)[1];
        qr[0] = a.x * scale; qr[1] = a.y * scale; qr[2] = a.z * scale; qr[3] = a.w * scale;
        qr[4] = b.x * scale; qr[5] = b.y * scale; qr[6] = b.z * scale; qr[7] = b.w * scale;
    }
    int sh = qy - 3; sh = sh < 0 ? 0 : (sh > 49 ? 49 : sh);
    int sw = qx - 3; sw = sw < 0 ? 0 : (sw > 49 ? 49 : sw);
    int dy0 = sh - h0, dx0 = sw - w0;          // 0..7
    int bh0 = sh - qy + 6, bw0 = sw - qx + 6;  // 0..6

    float sc[49];
    float mx = -1e30f;
    #pragma unroll
    for (int jh = 0; jh < 7; ++jh) {
        #pragma unroll
        for (int jw = 0; jw < 7; ++jw) {
            int nb = (dy0 + jh) * 14 + dx0 + jw;
            const float* kr = &Ks[nb][c * 8];
            float4 k0 = reinterpret_cast<const float4*>(kr)[0];
            float4 k1 = reinterpret_cast<const float4*>(kr)[1];
            float d = qr[0] * k0.x + qr[1] * k0.y + qr[2] * k0.z + qr[3] * k0.w
                    + qr[4] * k1.x + qr[5] * k1.y + qr[6] * k1.z + qr[7] * k1.w;
            d += __shfl_xor(d, 1, 64);
            d += __shfl_xor(d, 2, 64);          // all 4 lanes now hold full dot
            d += bs[(bh0 + jh) * 13 + bw0 + jw];
            sc[jh * 7 + jw] = d;
            mx = fmaxf(mx, d);
        }
    }
    float se = 0.f;
    #pragma unroll
    for (int j = 0; j < 49; ++j) { sc[j] = __expf(sc[j] - mx); se += sc[j]; }
    float inv = 1.0f / se;

    __syncthreads();   // everyone done reading K
    // stage V into the same buffer
    for (int idx = t; idx < 196 * 8; idx += 256) {
        int row = idx >> 3, seg = idx & 7;
        int iy = h0 + row / 14, ix = w0 + row % 14;
        int gpos = posbase + iy * WW + ix;
        *reinterpret_cast<float4*>(&Ks[row][seg * 4]) =
            *reinterpret_cast<const float4*>(&qkv[(size_t)gpos * 1152 + 768 + head * 32 + seg * 4]);
    }
    __syncthreads();

    float o[8] = {};
    #pragma unroll
    for (int jh = 0; jh < 7; ++jh) {
        #pragma unroll
        for (int jw = 0; jw < 7; ++jw) {
            int nb = (dy0 + jh) * 14 + dx0 + jw;
            float w = sc[jh * 7 + jw] * inv;
            const float* vr = &Ks[nb][c * 8];
            float4 v0 = reinterpret_cast<const float4*>(vr)[0];
            float4 v1 = reinterpret_cast<const float4*>(vr)[1];
            o[0] = fmaf(w, v0.x, o[0]); o[1] = fmaf(w, v0.y, o[1]);
            o[2] = fmaf(w, v0.z, o[2]); o[3] = fmaf(w, v0.w, o[3]);
            o[4] = fmaf(w, v1.x, o[4]); o[5] = fmaf(w, v1.y, o[5]);
            o[6] = fmaf(w, v1.z, o[6]); o[7] = fmaf(w, v1.w, o[7]);
        }
    }
    float* ob = &outp[(size_t)qpos * CC + head * 32 + c * 8];
    float4 r0 = {o[0], o[1], o[2], o[3]};
    float4 r1 = {o[4], o[5], o[6], o[7]};
    reinterpret_cast<float4*>(ob)[0] = r0;
    reinterpret_cast<float4*>(ob)[1] = r1;
}

extern "C" void kernel_launch(void* const* d_in, const int* in_sizes, int n_in,
                              void* d_out, int out_size, void* d_ws, size_t ws_size,
                              hipStream_t stream) {
    const float* x     = (const float*)d_in[0];
    const float* ln1g  = (const float*)d_in[1];
    const float* ln1b  = (const float*)d_in[2];
    const float* wqkv  = (const float*)d_in[3];
    const float* bqkv  = (const float*)d_in[4];
    const float* rpb   = (const float*)d_in[5];
    const float* wproj = (const float*)d_in[6];
    const float* bproj = (const float*)d_in[7];
    const float* ln2g  = (const float*)d_in[8];
    const float* ln2b  = (const float*)d_in[9];
    const float* w1    = (const float*)d_in[10];
    const float* b1    = (const float*)d_in[11];
    const float* w2    = (const float*)d_in[12];
    const float* b2    = (const float*)d_in[13];
    float* out = (float*)d_out;

    const int Nrows = 2 * HH * WW; // 6272
    char* ws = (char*)d_ws;
    // region 0: qkv (28.9MB) then reused as h1 (38.5MB)
    float* qkv = (float*)(ws);
    float* h1  = qkv;
    // region 1: y1 / attn_out / y2 (9.63MB)
    float* y1  = (float*)(ws + 38535168);
    // region 2: x2 (9.63MB)
    float* x2  = (float*)(ws + 38535168 + 9633792);

    // 1. LN1: y1 = layer_norm(x)
    ln_kernel<<<Nrows / 4, 256, 0, stream>>>(x, ln1g, ln1b, y1, Nrows);
    // 2. qkv = y1 @ w_qkv + b_qkv   (6272 x 384 x 1152)
    gemm_f32<0><<<dim3(1152 / 64, Nrows / 64), 256, 0, stream>>>(y1, wqkv, bqkv, nullptr, qkv, Nrows, 1152, 384);
    // 3. neighborhood attention -> attn_out (reuse y1 region)
    float* attn_out = y1;
    nattn_tile<<<dim3(49, NHEADS, 2), 256, 0, stream>>>(qkv, rpb, attn_out);
    // 4. x2 = x + attn_out @ w_proj + b_proj   (6272 x 384 x 384)
    gemm_f32<2><<<dim3(384 / 64, Nrows / 64), 256, 0, stream>>>(attn_out, wproj, bproj, x, x2, Nrows, 384, 384);
    // 5. LN2: y2 = layer_norm(x2) (reuse y1 region)
    float* y2 = y1;
    ln_kernel<<<Nrows / 4, 256, 0, stream>>>(x2, ln2g, ln2b, y2, Nrows);
    // 6. h1 = gelu(y2 @ w1 + b1)   (6272 x 384 x 1536)
    gemm_f32<1><<<dim3(HID / 64, Nrows / 64), 256, 0, stream>>>(y2, w1, b1, nullptr, h1, Nrows, HID, 384);
    // 7. out = x2 + h1 @ w2 + b2   (6272 x 1536 x 384)
    gemm_f32<2><<<dim3(384 / 64, Nrows / 64), 256, 0, stream>>>(h1, w2, b2, x2, out, Nrows, 384, HID);
}

// Round 5
// 151.763 us; speedup vs baseline: 3.7719x; 2.6199x over previous
//
#include <hip/hip_runtime.h>
#include <hip/hip_bf16.h>
#include <math.h>

#define HH 56
#define WW 56
#define CC 384
#define NHEADS 12
#define DHEAD 32
#define HID 1536

typedef short bf16x8 __attribute__((ext_vector_type(8)));
typedef float f32x4 __attribute__((ext_vector_type(4)));

__device__ __forceinline__ float gelu_exact(float v) {
    return 0.5f * v * (1.0f + erff(v * 0.70710678118654752f));
}
__device__ __forceinline__ unsigned short f2bf(float f) {
    __hip_bfloat16 h = __float2bfloat16(f);
    unsigned short u; __builtin_memcpy(&u, &h, 2); return u;
}

// ---------------- weight convert + transpose: Wt[n][k] = bf16(W[k][n]) ----------------
__global__ __launch_bounds__(256) void wconv(const float* __restrict__ W,
        unsigned short* __restrict__ Wt, int K, int N) {
    int tid = blockIdx.x * 256 + threadIdx.x;
    int total = (K >> 3) * N;
    if (tid >= total) return;
    int n = tid % N, kc = tid / N;
    unsigned short tmp[8];
    #pragma unroll
    for (int j = 0; j < 8; ++j)
        tmp[j] = f2bf(W[(size_t)(kc * 8 + j) * N + n]);
    *reinterpret_cast<uint4*>(&Wt[(size_t)n * K + kc * 8]) = *reinterpret_cast<uint4*>(tmp);
}

// ---------------- LayerNorm: one wave per row of 384, bf16 output ----------------
__global__ __launch_bounds__(256) void ln_bf16(const float* __restrict__ x,
        const float* __restrict__ g, const float* __restrict__ b,
        unsigned short* __restrict__ y, int nrows) {
    int wid = (blockIdx.x * 256 + threadIdx.x) >> 6;
    int lane = threadIdx.x & 63;
    if (wid >= nrows) return;
    const float* xr = x + (size_t)wid * CC;
    float v[6];
    float s = 0.f, s2 = 0.f;
    #pragma unroll
    for (int j = 0; j < 6; ++j) {
        v[j] = xr[lane + j * 64];
        s += v[j]; s2 += v[j] * v[j];
    }
    #pragma unroll
    for (int o = 1; o < 64; o <<= 1) {
        s  += __shfl_xor(s, o, 64);
        s2 += __shfl_xor(s2, o, 64);
    }
    float mu  = s * (1.0f / CC);
    float var = s2 * (1.0f / CC) - mu * mu;
    float rs  = rsqrtf(var + 1e-5f);
    unsigned short* yr = y + (size_t)wid * CC;
    #pragma unroll
    for (int j = 0; j < 6; ++j) {
        int c = lane + j * 64;
        yr[c] = f2bf((v[j] - mu) * rs * g[c] + b[c]);
    }
}

// ---------------- bf16 MFMA GEMM: out = A[MxK] @ Wt[NxK]^T + bias, epilogues ----------------
// EPI: 0 = bias, 1 = bias+gelu, 2 = bias+residual.  OUTBF: 1 = bf16 out, 0 = f32 out.
// 128x128 tile, 4 waves, each wave 64x64 (4x4 mfma_f32_16x16x32_bf16 frags), BK=32.
template<int EPI, int OUTBF>
__global__ __launch_bounds__(256) void gemm_mfma(
        const unsigned short* __restrict__ A,
        const unsigned short* __restrict__ Bt,
        const float* __restrict__ bias,
        const float* __restrict__ res,
        void* __restrict__ outv,
        int M, int N, int K) {
    constexpr int LDS_ = 40;  // padded bf16 stride (20 words: spreads bank quads)
    __shared__ unsigned short As[128 * LDS_];
    __shared__ unsigned short Bs[128 * LDS_];
    int tid = threadIdx.x;
    int m0 = blockIdx.y * 128, n0 = blockIdx.x * 128;
    int w = tid >> 6, lane = tid & 63;
    int wr = w >> 1, wc = w & 1;
    int l15 = lane & 15, l4 = lane >> 4;
    int sc_ = tid & 3, sr_ = tid >> 2;   // staging: 16B chunk, row 0..63 (+64)

    f32x4 acc[4][4] = {};
    for (int k0 = 0; k0 < K; k0 += 32) {
        #pragma unroll
        for (int h = 0; h < 2; ++h) {
            int row = sr_ + h * 64;
            uint4 va = *reinterpret_cast<const uint4*>(&A[(size_t)(m0 + row) * K + k0 + sc_ * 8]);
            *reinterpret_cast<uint4*>(&As[row * LDS_ + sc_ * 8]) = va;
            uint4 vb = *reinterpret_cast<const uint4*>(&Bt[(size_t)(n0 + row) * K + k0 + sc_ * 8]);
            *reinterpret_cast<uint4*>(&Bs[row * LDS_ + sc_ * 8]) = vb;
        }
        __syncthreads();
        bf16x8 af[4], bfr[4];
        #pragma unroll
        for (int i = 0; i < 4; ++i)
            af[i] = *reinterpret_cast<const bf16x8*>(&As[(wr * 64 + i * 16 + l15) * LDS_ + l4 * 8]);
        #pragma unroll
        for (int j = 0; j < 4; ++j)
            bfr[j] = *reinterpret_cast<const bf16x8*>(&Bs[(wc * 64 + j * 16 + l15) * LDS_ + l4 * 8]);
        #pragma unroll
        for (int i = 0; i < 4; ++i)
            #pragma unroll
            for (int j = 0; j < 4; ++j)
                acc[i][j] = __builtin_amdgcn_mfma_f32_16x16x32_bf16(af[i], bfr[j], acc[i][j], 0, 0, 0);
        __syncthreads();
    }
    float* outf = (float*)outv;
    unsigned short* outh = (unsigned short*)outv;
    #pragma unroll
    for (int i = 0; i < 4; ++i) {
        #pragma unroll
        for (int r = 0; r < 4; ++r) {
            int grow = m0 + wr * 64 + i * 16 + l4 * 4 + r;
            #pragma unroll
            for (int j = 0; j < 4; ++j) {
                int gcol = n0 + wc * 64 + j * 16 + l15;
                float v = acc[i][j][r] + bias[gcol];
                if (EPI == 1) v = gelu_exact(v);
                if (EPI == 2) v += res[(size_t)grow * N + gcol];
                if (OUTBF) outh[(size_t)grow * N + gcol] = f2bf(v);
                else       outf[(size_t)grow * N + gcol] = v;
            }
        }
    }
}

// ---------------- Tiled neighborhood attention (bf16 output) ----------------
__global__ __launch_bounds__(256) void nattn_tile(const float* __restrict__ qkv,
        const float* __restrict__ rpb, unsigned short* __restrict__ outp) {
    __shared__ float Ks[196][36];
    __shared__ float bs[169];
    int tile = blockIdx.x;
    int head = blockIdx.y;
    int bat  = blockIdx.z;
    int tly = tile / 7, tlx = tile % 7;
    int h0 = tly * 8 - 3; h0 = h0 < 0 ? 0 : (h0 > 42 ? 42 : h0);
    int w0 = tlx * 8 - 3; w0 = w0 < 0 ? 0 : (w0 > 42 ? 42 : w0);
    int t = threadIdx.x;
    int posbase = bat * (HH * WW);

    for (int i = t; i < 169; i += 256) bs[i] = rpb[head * 169 + i];
    for (int idx = t; idx < 196 * 8; idx += 256) {
        int row = idx >> 3, seg = idx & 7;
        int iy = h0 + row / 14, ix = w0 + row % 14;
        int gpos = posbase + iy * WW + ix;
        *reinterpret_cast<float4*>(&Ks[row][seg * 4]) =
            *reinterpret_cast<const float4*>(&qkv[(size_t)gpos * 1152 + 384 + head * 32 + seg * 4]);
    }
    __syncthreads();

    int q = t >> 2, c = t & 3;
    int qy = tly * 8 + (q >> 3), qx = tlx * 8 + (q & 7);
    int qpos = posbase + qy * WW + qx;
    const float scale = 0.17677669529663687f;
    float qr[8];
    {
        const float* qb = &qkv[(size_t)qpos * 1152 + head * 32 + c * 8];
        float4 a = reinterpret_cast<const float4*>(qb)[0];
        float4 b = reinterpret_cast<const float4*>(qb)[1];
        qr[0] = a.x * scale; qr[1] = a.y * scale; qr[2] = a.z * scale; qr[3] = a.w * scale;
        qr[4] = b.x * scale; qr[5] = b.y * scale; qr[6] = b.z * scale; qr[7] = b.w * scale;
    }
    int sh = qy - 3; sh = sh < 0 ? 0 : (sh > 49 ? 49 : sh);
    int sw = qx - 3; sw = sw < 0 ? 0 : (sw > 49 ? 49 : sw);
    int dy0 = sh - h0, dx0 = sw - w0;
    int bh0 = sh - qy + 6, bw0 = sw - qx + 6;

    float sc[49];
    float mx = -1e30f;
    #pragma unroll
    for (int jh = 0; jh < 7; ++jh) {
        #pragma unroll
        for (int jw = 0; jw < 7; ++jw) {
            int nb = (dy0 + jh) * 14 + dx0 + jw;
            const float* kr = &Ks[nb][c * 8];
            float4 k0 = reinterpret_cast<const float4*>(kr)[0];
            float4 k1 = reinterpret_cast<const float4*>(kr)[1];
            float d = qr[0] * k0.x + qr[1] * k0.y + qr[2] * k0.z + qr[3] * k0.w
                    + qr[4] * k1.x + qr[5] * k1.y + qr[6] * k1.z + qr[7] * k1.w;
            d += __shfl_xor(d, 1, 64);
            d += __shfl_xor(d, 2, 64);
            d += bs[(bh0 + jh) * 13 + bw0 + jw];
            sc[jh * 7 + jw] = d;
            mx = fmaxf(mx, d);
        }
    }
    float se = 0.f;
    #pragma unroll
    for (int j = 0; j < 49; ++j) { sc[j] = __expf(sc[j] - mx); se += sc[j]; }
    float inv = 1.0f / se;

    __syncthreads();
    for (int idx = t; idx < 196 * 8; idx += 256) {
        int row = idx >> 3, seg = idx & 7;
        int iy = h0 + row / 14, ix = w0 + row % 14;
        int gpos = posbase + iy * WW + ix;
        *reinterpret_cast<float4*>(&Ks[row][seg * 4]) =
            *reinterpret_cast<const float4*>(&qkv[(size_t)gpos * 1152 + 768 + head * 32 + seg * 4]);
    }
    __syncthreads();

    float o[8] = {};
    #pragma unroll
    for (int jh = 0; jh < 7; ++jh) {
        #pragma unroll
        for (int jw = 0; jw < 7; ++jw) {
            int nb = (dy0 + jh) * 14 + dx0 + jw;
            float w = sc[jh * 7 + jw] * inv;
            const float* vr = &Ks[nb][c * 8];
            float4 v0 = reinterpret_cast<const float4*>(vr)[0];
            float4 v1 = reinterpret_cast<const float4*>(vr)[1];
            o[0] = fmaf(w, v0.x, o[0]); o[1] = fmaf(w, v0.y, o[1]);
            o[2] = fmaf(w, v0.z, o[2]); o[3] = fmaf(w, v0.w, o[3]);
            o[4] = fmaf(w, v1.x, o[4]); o[5] = fmaf(w, v1.y, o[5]);
            o[6] = fmaf(w, v1.z, o[6]); o[7] = fmaf(w, v1.w, o[7]);
        }
    }
    unsigned short oh[8];
    #pragma unroll
    for (int i = 0; i < 8; ++i) oh[i] = f2bf(o[i]);
    *reinterpret_cast<uint4*>(&outp[(size_t)qpos * CC + head * 32 + c * 8]) =
        *reinterpret_cast<uint4*>(oh);
}

extern "C" void kernel_launch(void* const* d_in, const int* in_sizes, int n_in,
                              void* d_out, int out_size, void* d_ws, size_t ws_size,
                              hipStream_t stream) {
    const float* x     = (const float*)d_in[0];
    const float* ln1g  = (const float*)d_in[1];
    const float* ln1b  = (const float*)d_in[2];
    const float* wqkv  = (const float*)d_in[3];
    const float* bqkv  = (const float*)d_in[4];
    const float* rpb   = (const float*)d_in[5];
    const float* wproj = (const float*)d_in[6];
    const float* bproj = (const float*)d_in[7];
    const float* ln2g  = (const float*)d_in[8];
    const float* ln2b  = (const float*)d_in[9];
    const float* w1    = (const float*)d_in[10];
    const float* b1    = (const float*)d_in[11];
    const float* w2    = (const float*)d_in[12];
    const float* b2    = (const float*)d_in[13];
    float* out = (float*)d_out;

    const int Nrows = 2 * HH * WW; // 6272
    char* ws = (char*)d_ws;
    // layout (bytes):
    float*          qkv   = (float*)(ws);                        // 6272*1152*4 = 28,901,376
    unsigned short* h1    = (unsigned short*)(ws);               // reuse: 6272*1536*2 = 19.3MB
    unsigned short* y1    = (unsigned short*)(ws + 28901376);    // 6272*384*2 = 4,816,896 (also attn_out, y2)
    float*          x2    = (float*)(ws + 33718272);             // 6272*384*4 = 9,633,792
    unsigned short* wqkvT = (unsigned short*)(ws + 43352064);    // 384*1152*2 = 884,736
    unsigned short* wprojT= (unsigned short*)(ws + 44236800);    // 384*384*2  = 294,912
    unsigned short* w1T   = (unsigned short*)(ws + 44531712);    // 384*1536*2 = 1,179,648
    unsigned short* w2T   = (unsigned short*)(ws + 45711360);    // 1536*384*2 = 1,179,648

    // 0. weight conversions (bf16, transposed)
    wconv<<<(384/8*1152 + 255)/256, 256, 0, stream>>>(wqkv, wqkvT, 384, 1152);
    wconv<<<(384/8*384  + 255)/256, 256, 0, stream>>>(wproj, wprojT, 384, 384);
    wconv<<<(384/8*1536 + 255)/256, 256, 0, stream>>>(w1, w1T, 384, 1536);
    wconv<<<(1536/8*384 + 255)/256, 256, 0, stream>>>(w2, w2T, 1536, 384);

    // 1. LN1 -> y1 (bf16)
    ln_bf16<<<Nrows / 4, 256, 0, stream>>>(x, ln1g, ln1b, y1, Nrows);
    // 2. qkv = y1 @ w_qkv + b_qkv (f32 out)
    gemm_mfma<0,0><<<dim3(1152/128, Nrows/128), 256, 0, stream>>>(y1, wqkvT, bqkv, nullptr, qkv, Nrows, 1152, 384);
    // 3. neighborhood attention -> attn_out (bf16, reuse y1)
    unsigned short* attn_out = y1;
    nattn_tile<<<dim3(49, NHEADS, 2), 256, 0, stream>>>(qkv, rpb, attn_out);
    // 4. x2 = x + attn_out @ w_proj + b_proj (f32 out)
    gemm_mfma<2,0><<<dim3(384/128, Nrows/128), 256, 0, stream>>>(attn_out, wprojT, bproj, x, x2, Nrows, 384, 384);
    // 5. LN2 -> y2 (bf16, reuse y1)
    unsigned short* y2 = y1;
    ln_bf16<<<Nrows / 4, 256, 0, stream>>>(x2, ln2g, ln2b, y2, Nrows);
    // 6. h1 = gelu(y2 @ w1 + b1) (bf16 out, reuse qkv region)
    gemm_mfma<1,1><<<dim3(HID/128, Nrows/128), 256, 0, stream>>>(y2, w1T, b1, nullptr, h1, Nrows, HID, 384);
    // 7. out = x2 + h1 @ w2 + b2 (f32 out)
    gemm_mfma<2,0><<<dim3(384/128, Nrows/128), 256, 0, stream>>>(h1, w2T, b2, x2, out, Nrows, 384, HID);
}

// Round 6
// 127.062 us; speedup vs baseline: 4.5051x; 1.1944x over previous
//
#include <hip/hip_runtime.h>
#include <hip/hip_bf16.h>
#include <math.h>

#define HH 56
#define WW 56
#define CC 384
#define NHEADS 12
#define DHEAD 32
#define HID 1536

typedef short bf16x8 __attribute__((ext_vector_type(8)));
typedef float f32x4 __attribute__((ext_vector_type(4)));

__device__ __forceinline__ float gelu_exact(float v) {
    return 0.5f * v * (1.0f + erff(v * 0.70710678118654752f));
}
__device__ __forceinline__ unsigned short f2bf(float f) {
    __hip_bfloat16 h = __float2bfloat16(f);
    unsigned short u; __builtin_memcpy(&u, &h, 2); return u;
}
__device__ __forceinline__ void gload16(unsigned short* lds, const unsigned short* g) {
    __builtin_amdgcn_global_load_lds(
        (const __attribute__((address_space(1))) void*)g,
        (__attribute__((address_space(3))) void*)lds, 16, 0, 0);
}

// ---------------- weight convert + transpose: Wt[n][k] = bf16(W[k][n]) ----------------
__global__ __launch_bounds__(256) void wconv(const float* __restrict__ W,
        unsigned short* __restrict__ Wt, int K, int N) {
    int tid = blockIdx.x * 256 + threadIdx.x;
    int total = (K >> 3) * N;
    if (tid >= total) return;
    int n = tid % N, kc = tid / N;
    unsigned short tmp[8];
    #pragma unroll
    for (int j = 0; j < 8; ++j)
        tmp[j] = f2bf(W[(size_t)(kc * 8 + j) * N + n]);
    *reinterpret_cast<uint4*>(&Wt[(size_t)n * K + kc * 8]) = *reinterpret_cast<uint4*>(tmp);
}

// ---------------- LayerNorm: one wave per row of 384, bf16 output ----------------
__global__ __launch_bounds__(256) void ln_bf16(const float* __restrict__ x,
        const float* __restrict__ g, const float* __restrict__ b,
        unsigned short* __restrict__ y, int nrows) {
    int wid = (blockIdx.x * 256 + threadIdx.x) >> 6;
    int lane = threadIdx.x & 63;
    if (wid >= nrows) return;
    const float* xr = x + (size_t)wid * CC;
    float v[6];
    float s = 0.f, s2 = 0.f;
    #pragma unroll
    for (int j = 0; j < 6; ++j) {
        v[j] = xr[lane + j * 64];
        s += v[j]; s2 += v[j] * v[j];
    }
    #pragma unroll
    for (int o = 1; o < 64; o <<= 1) {
        s  += __shfl_xor(s, o, 64);
        s2 += __shfl_xor(s2, o, 64);
    }
    float mu  = s * (1.0f / CC);
    float var = s2 * (1.0f / CC) - mu * mu;
    float rs  = rsqrtf(var + 1e-5f);
    unsigned short* yr = y + (size_t)wid * CC;
    #pragma unroll
    for (int j = 0; j < 6; ++j) {
        int c = lane + j * 64;
        yr[c] = f2bf((v[j] - mu) * rs * g[c] + b[c]);
    }
}

// ---------------- bf16 MFMA GEMM: out = A[MxK] @ Bt[NxK]^T + bias ----------------
// BM=BN=64, BK=64, 4 waves (32x32 each). Double-buffered LDS via global_load_lds
// with XOR-swizzled source (slot t of row r holds global chunk t^(r&7)).
// EPI: 0 = bias, 1 = bias+gelu, 2 = bias+residual. OUTBF: 1 = bf16 out, 0 = f32.
template<int EPI, int OUTBF>
__global__ __launch_bounds__(256) void gemm_mfma(
        const unsigned short* __restrict__ A,
        const unsigned short* __restrict__ Bt,
        const float* __restrict__ bias,
        const float* __restrict__ res,
        void* __restrict__ outv,
        int M, int N, int K) {
    __shared__ unsigned short As[2][64 * 64];
    __shared__ unsigned short Bs[2][64 * 64];
    int tid = threadIdx.x;
    int m0 = blockIdx.y * 64, n0 = blockIdx.x * 64;
    int w = tid >> 6, lane = tid & 63;
    int wm = w >> 1, wn = w & 1;
    int l15 = lane & 15, l4 = lane >> 4;

    // staging: wave w stages 8-row groups {2w, 2w+1} of both A and B.
    // lane l -> row (l>>3) within group, source chunk (l&7)^(l>>3) (inverse swizzle).
    int srow = lane >> 3;
    int schunk = (lane & 7) ^ srow;
    int g0 = w * 2, g1 = g0 + 1;
    const unsigned short* Ag0 = A  + (size_t)(m0 + g0 * 8 + srow) * K + schunk * 8;
    const unsigned short* Ag1 = A  + (size_t)(m0 + g1 * 8 + srow) * K + schunk * 8;
    const unsigned short* Bg0 = Bt + (size_t)(n0 + g0 * 8 + srow) * K + schunk * 8;
    const unsigned short* Bg1 = Bt + (size_t)(n0 + g1 * 8 + srow) * K + schunk * 8;

    // read-side swizzled chunk for kk=0: c0 = l4 ^ (l15&7); kk=1 flips bit 2.
    int c0 = (l4 ^ (l15 & 7)) * 8;
    int arow0 = (wm * 32 + l15) * 64;        // af[0] row base (shorts)
    int brow0 = (wn * 32 + l15) * 64;

    f32x4 acc[2][2] = {};
    int nt = K >> 6;
    gload16(&As[0][g0 * 512], Ag0);
    gload16(&As[0][g1 * 512], Ag1);
    gload16(&Bs[0][g0 * 512], Bg0);
    gload16(&Bs[0][g1 * 512], Bg1);
    __syncthreads();
    int buf = 0;
    for (int t = 0; t < nt; ++t) {
        if (t + 1 < nt) {
            int k0 = (t + 1) << 6;
            gload16(&As[buf ^ 1][g0 * 512], Ag0 + k0);
            gload16(&As[buf ^ 1][g1 * 512], Ag1 + k0);
            gload16(&Bs[buf ^ 1][g0 * 512], Bg0 + k0);
            gload16(&Bs[buf ^ 1][g1 * 512], Bg1 + k0);
        }
        const unsigned short* as = As[buf];
        const unsigned short* bs = Bs[buf];
        #pragma unroll
        for (int kk = 0; kk < 2; ++kk) {
            int c = c0 ^ (kk * 32);          // chunk elt offset (c^4)*8 == c0^32
            bf16x8 af0 = *reinterpret_cast<const bf16x8*>(&as[arow0 + c]);
            bf16x8 af1 = *reinterpret_cast<const bf16x8*>(&as[arow0 + 16 * 64 + c]);
            bf16x8 bf0 = *reinterpret_cast<const bf16x8*>(&bs[brow0 + c]);
            bf16x8 bf1 = *reinterpret_cast<const bf16x8*>(&bs[brow0 + 16 * 64 + c]);
            acc[0][0] = __builtin_amdgcn_mfma_f32_16x16x32_bf16(af0, bf0, acc[0][0], 0, 0, 0);
            acc[0][1] = __builtin_amdgcn_mfma_f32_16x16x32_bf16(af0, bf1, acc[0][1], 0, 0, 0);
            acc[1][0] = __builtin_amdgcn_mfma_f32_16x16x32_bf16(af1, bf0, acc[1][0], 0, 0, 0);
            acc[1][1] = __builtin_amdgcn_mfma_f32_16x16x32_bf16(af1, bf1, acc[1][1], 0, 0, 0);
        }
        __syncthreads();
        buf ^= 1;
    }
    float* outf = (float*)outv;
    unsigned short* outh = (unsigned short*)outv;
    #pragma unroll
    for (int j = 0; j < 2; ++j) {
        int gcol = n0 + wn * 32 + j * 16 + l15;
        float bv = bias[gcol];
        #pragma unroll
        for (int i = 0; i < 2; ++i) {
            #pragma unroll
            for (int r = 0; r < 4; ++r) {
                int grow = m0 + wm * 32 + i * 16 + l4 * 4 + r;
                float v = acc[i][j][r] + bv;
                if (EPI == 1) v = gelu_exact(v);
                if (EPI == 2) v += res[(size_t)grow * N + gcol];
                if (OUTBF) outh[(size_t)grow * N + gcol] = f2bf(v);
                else       outf[(size_t)grow * N + gcol] = v;
            }
        }
    }
}

// ---------------- Tiled neighborhood attention (bf16 output) ----------------
__global__ __launch_bounds__(256) void nattn_tile(const float* __restrict__ qkv,
        const float* __restrict__ rpb, unsigned short* __restrict__ outp) {
    __shared__ float Ks[196][36];
    __shared__ float bs[169];
    int tile = blockIdx.x;
    int head = blockIdx.y;
    int bat  = blockIdx.z;
    int tly = tile / 7, tlx = tile % 7;
    int h0 = tly * 8 - 3; h0 = h0 < 0 ? 0 : (h0 > 42 ? 42 : h0);
    int w0 = tlx * 8 - 3; w0 = w0 < 0 ? 0 : (w0 > 42 ? 42 : w0);
    int t = threadIdx.x;
    int posbase = bat * (HH * WW);

    for (int i = t; i < 169; i += 256) bs[i] = rpb[head * 169 + i];
    for (int idx = t; idx < 196 * 8; idx += 256) {
        int row = idx >> 3, seg = idx & 7;
        int iy = h0 + row / 14, ix = w0 + row % 14;
        int gpos = posbase + iy * WW + ix;
        *reinterpret_cast<float4*>(&Ks[row][seg * 4]) =
            *reinterpret_cast<const float4*>(&qkv[(size_t)gpos * 1152 + 384 + head * 32 + seg * 4]);
    }
    __syncthreads();

    int q = t >> 2, c = t & 3;
    int qy = tly * 8 + (q >> 3), qx = tlx * 8 + (q & 7);
    int qpos = posbase + qy * WW + qx;
    const float scale = 0.17677669529663687f;
    float qr[8];
    {
        const float* qb = &qkv[(size_t)qpos * 1152 + head * 32 + c * 8];
        float4 a = reinterpret_cast<const float4*>(qb)[0];
        float4 b = reinterpret_cast<const float4*>(qb)[1];
        qr[0] = a.x * scale; qr[1] = a.y * scale; qr[2] = a.z * scale; qr[3] = a.w * scale;
        qr[4] = b.x * scale; qr[5] = b.y * scale; qr[6] = b.z * scale; qr[7] = b.w * scale;
    }
    int sh = qy - 3; sh = sh < 0 ? 0 : (sh > 49 ? 49 : sh);
    int sw = qx - 3; sw = sw < 0 ? 0 : (sw > 49 ? 49 : sw);
    int dy0 = sh - h0, dx0 = sw - w0;
    int bh0 = sh - qy + 6, bw0 = sw - qx + 6;

    float sc[49];
    float mx = -1e30f;
    #pragma unroll
    for (int jh = 0; jh < 7; ++jh) {
        #pragma unroll
        for (int jw = 0; jw < 7; ++jw) {
            int nb = (dy0 + jh) * 14 + dx0 + jw;
            const float* kr = &Ks[nb][c * 8];
            float4 k0 = reinterpret_cast<const float4*>(kr)[0];
            float4 k1 = reinterpret_cast<const float4*>(kr)[1];
            float d = qr[0] * k0.x + qr[1] * k0.y + qr[2] * k0.z + qr[3] * k0.w
                    + qr[4] * k1.x + qr[5] * k1.y + qr[6] * k1.z + qr[7] * k1.w;
            d += __shfl_xor(d, 1, 64);
            d += __shfl_xor(d, 2, 64);
            d += bs[(bh0 + jh) * 13 + bw0 + jw];
            sc[jh * 7 + jw] = d;
            mx = fmaxf(mx, d);
        }
    }
    float se = 0.f;
    #pragma unroll
    for (int j = 0; j < 49; ++j) { sc[j] = __expf(sc[j] - mx); se += sc[j]; }
    float inv = 1.0f / se;

    __syncthreads();
    for (int idx = t; idx < 196 * 8; idx += 256) {
        int row = idx >> 3, seg = idx & 7;
        int iy = h0 + row / 14, ix = w0 + row % 14;
        int gpos = posbase + iy * WW + ix;
        *reinterpret_cast<float4*>(&Ks[row][seg * 4]) =
            *reinterpret_cast<const float4*>(&qkv[(size_t)gpos * 1152 + 768 + head * 32 + seg * 4]);
    }
    __syncthreads();

    float o[8] = {};
    #pragma unroll
    for (int jh = 0; jh < 7; ++jh) {
        #pragma unroll
        for (int jw = 0; jw < 7; ++jw) {
            int nb = (dy0 + jh) * 14 + dx0 + jw;
            float w = sc[jh * 7 + jw] * inv;
            const float* vr = &Ks[nb][c * 8];
            float4 v0 = reinterpret_cast<const float4*>(vr)[0];
            float4 v1 = reinterpret_cast<const float4*>(vr)[1];
            o[0] = fmaf(w, v0.x, o[0]); o[1] = fmaf(w, v0.y, o[1]);
            o[2] = fmaf(w, v0.z, o[2]); o[3] = fmaf(w, v0.w, o[3]);
            o[4] = fmaf(w, v1.x, o[4]); o[5] = fmaf(w, v1.y, o[5]);
            o[6] = fmaf(w, v1.z, o[6]); o[7] = fmaf(w, v1.w, o[7]);
        }
    }
    unsigned short oh[8];
    #pragma unroll
    for (int i = 0; i < 8; ++i) oh[i] = f2bf(o[i]);
    *reinterpret_cast<uint4*>(&outp[(size_t)qpos * CC + head * 32 + c * 8]) =
        *reinterpret_cast<uint4*>(oh);
}

extern "C" void kernel_launch(void* const* d_in, const int* in_sizes, int n_in,
                              void* d_out, int out_size, void* d_ws, size_t ws_size,
                              hipStream_t stream) {
    const float* x     = (const float*)d_in[0];
    const float* ln1g  = (const float*)d_in[1];
    const float* ln1b  = (const float*)d_in[2];
    const float* wqkv  = (const float*)d_in[3];
    const float* bqkv  = (const float*)d_in[4];
    const float* rpb   = (const float*)d_in[5];
    const float* wproj = (const float*)d_in[6];
    const float* bproj = (const float*)d_in[7];
    const float* ln2g  = (const float*)d_in[8];
    const float* ln2b  = (const float*)d_in[9];
    const float* w1    = (const float*)d_in[10];
    const float* b1    = (const float*)d_in[11];
    const float* w2    = (const float*)d_in[12];
    const float* b2    = (const float*)d_in[13];
    float* out = (float*)d_out;

    const int Nrows = 2 * HH * WW; // 6272
    char* ws = (char*)d_ws;
    float*          qkv   = (float*)(ws);                        // 28,901,376 B
    unsigned short* h1    = (unsigned short*)(ws);               // reuse (19.3MB)
    unsigned short* y1    = (unsigned short*)(ws + 28901376);    // 4,816,896 B
    float*          x2    = (float*)(ws + 33718272);             // 9,633,792 B
    unsigned short* wqkvT = (unsigned short*)(ws + 43352064);    // 884,736 B
    unsigned short* wprojT= (unsigned short*)(ws + 44236800);    // 294,912 B
    unsigned short* w1T   = (unsigned short*)(ws + 44531712);    // 1,179,648 B
    unsigned short* w2T   = (unsigned short*)(ws + 45711360);    // 1,179,648 B

    // 0. weight conversions (bf16, transposed)
    wconv<<<(384/8*1152 + 255)/256, 256, 0, stream>>>(wqkv, wqkvT, 384, 1152);
    wconv<<<(384/8*384  + 255)/256, 256, 0, stream>>>(wproj, wprojT, 384, 384);
    wconv<<<(384/8*1536 + 255)/256, 256, 0, stream>>>(w1, w1T, 384, 1536);
    wconv<<<(1536/8*384 + 255)/256, 256, 0, stream>>>(w2, w2T, 1536, 384);

    // 1. LN1 -> y1 (bf16)
    ln_bf16<<<Nrows / 4, 256, 0, stream>>>(x, ln1g, ln1b, y1, Nrows);
    // 2. qkv = y1 @ w_qkv + b_qkv (f32 out)
    gemm_mfma<0,0><<<dim3(1152/64, Nrows/64), 256, 0, stream>>>(y1, wqkvT, bqkv, nullptr, qkv, Nrows, 1152, 384);
    // 3. neighborhood attention -> attn_out (bf16, reuse y1)
    unsigned short* attn_out = y1;
    nattn_tile<<<dim3(49, NHEADS, 2), 256, 0, stream>>>(qkv, rpb, attn_out);
    // 4. x2 = x + attn_out @ w_proj + b_proj (f32 out)
    gemm_mfma<2,0><<<dim3(384/64, Nrows/64), 256, 0, stream>>>(attn_out, wprojT, bproj, x, x2, Nrows, 384, 384);
    // 5. LN2 -> y2 (bf16, reuse y1)
    unsigned short* y2 = y1;
    ln_bf16<<<Nrows / 4, 256, 0, stream>>>(x2, ln2g, ln2b, y2, Nrows);
    // 6. h1 = gelu(y2 @ w1 + b1) (bf16 out, reuse qkv region)
    gemm_mfma<1,1><<<dim3(HID/64, Nrows/64), 256, 0, stream>>>(y2, w1T, b1, nullptr, h1, Nrows, HID, 384);
    // 7. out = x2 + h1 @ w2 + b2 (f32 out)
    gemm_mfma<2,0><<<dim3(384/64, Nrows/64), 256, 0, stream>>>(h1, w2T, b2, x2, out, Nrows, 384, HID);
}